// Round 20
// baseline (40.301 us; speedup 1.0000x reference)
//
#include <hip/hip_runtime.h>

#define NQ 12
#define NL 4
#define NGATES (NQ * NL)
#define INV_2PI 0.15915494309189535f

// ---------------------------------------------------------------------------
// Diagonalized formulation, 512 thr/elem, 8 amps/thread (r20).
// Every compiled gate is exp(-i th/2 X_m) -> all 48 commute; conjugating by
// H^x12 diagonalizes the circuit: U = H D H, D|q> = e^{-iPhi(q)}|q>,
//   Phi(q) = sum_g (th_g/2)(-1)^{parity(q & m_g)}  (layer-1 included).
// <Z_w> = sum_q conj(psi(q^rho_w)) psi(q), rho_w = row of L^-1 (HZH = X);
// psi = A e^{-iPhi}, A real product state (a0 = cy+sy, a1 = cy-sy, scale 2^-6).
// Layout (A = I): p[2:0] = reg (qubits 11,10,9); p[3+i] = tid bit i, i=0..8
// (qubit 8-i): lane = tid[5:0], wave bits = tid[8:6]. Masks' thread part =
// (m>>3) & 0x1FF.
// R20 RATIONALE: r17/r19 sat at ~33 us = 2x the ~16 us issue floor --
// latency-exposed at wpe(3)'s 3 waves/SIMD (WHT/doubling/reduce chains).
// wpe(4) spilled at ~90-float demand (r14/16/18). Halving per-thread state
// (8 amps: st 16 + A 8 + W 8 -> peak ~35 floats) fits wpe(4)'s 64-arch half
// -> 4 waves/SIMD AND halves every serial chain. Tripwire: WRITE_SIZE >>
// output => revert to wpe(3).
// Phase 2 accumulates RAW +-wts[g] (uniform s_loads), scales once (r17).
// Per-element trig table in LDS (r18). Correlations: cheap lane masks via
// DPP/permlane; others via ONE full LDS stash (32 KB, one barrier), stash
// written before the DPP lags so DS latency hides under VALU.
// ---------------------------------------------------------------------------
struct Masks { unsigned rx[NGATES]; unsigned z[NQ]; };

constexpr Masks compute_masks() {
  Masks mk{};
  unsigned col[NQ] = {};
  for (int b = 0; b < NQ; ++b) col[b] = 1u << b;
  int g = 0;
  for (int l = 0; l < NL; ++l) {
    for (int w = 0; w < NQ; ++w) mk.rx[g++] = col[NQ - 1 - w];
    for (int i = 0; i < NQ; ++i) {           // ring CNOT(i, (i+1)%12)
      int cb = NQ - 1 - i;
      int tb = NQ - 1 - ((i + 1) % NQ);
      col[cb] ^= col[tb];
    }
  }
  unsigned A[NQ] = {}, Inv[NQ] = {};
  for (int i = 0; i < NQ; ++i) {
    unsigned rowv = 0;
    for (int j = 0; j < NQ; ++j) rowv |= ((col[j] >> i) & 1u) << j;
    A[i] = rowv;
    Inv[i] = 1u << i;
  }
  for (int c = 0; c < NQ; ++c) {
    int piv = c;
    while (((A[piv] >> c) & 1u) == 0u) ++piv;
    unsigned ta = A[piv]; A[piv] = A[c]; A[c] = ta;
    unsigned ti = Inv[piv]; Inv[piv] = Inv[c]; Inv[c] = ti;
    for (int r = 0; r < NQ; ++r)
      if (r != c && ((A[r] >> c) & 1u)) { A[r] ^= A[c]; Inv[r] ^= Inv[c]; }
  }
  for (int w = 0; w < NQ; ++w) mk.z[w] = Inv[NQ - 1 - w];
  return mk;
}

constexpr Masks MK = compute_masks();

typedef float v2f __attribute__((ext_vector_type(2)));
typedef int   v2i __attribute__((ext_vector_type(2)));

template <int CTRL>
__device__ __forceinline__ int dpp_i(int x) {
  return __builtin_amdgcn_update_dpp(x, x, CTRL, 0xf, 0xf, false);
}

// VALU cost of a cross-lane xor-mask fetch (DPP/permlane path).
constexpr int dppcost(int ml) {
  int m4 = ml & 15;
  int c = (m4 == 0) ? 0
        : ((m4 == 1 || m4 == 2 || m4 == 3 || m4 == 7 || m4 == 8 || m4 == 15) ? 1 : 2);
  if (ml & 16) c += 2;
  if (ml & 32) c += 2;
  return c;
}

// v[lane ^ ML] on the VALU pipe. quad_perm xor1=0xB1 xor2=0x4E xor3=0x1B;
// row_half_mirror(xor7)=0x141; row_ror:8(xor8)=0x128; row_mirror(xor15)=0x140.
template <int ML>
__device__ __forceinline__ float fetchx(float v) {
  static_assert(ML >= 1 && ML < 64, "lane mask");
  int x = __float_as_int(v);
  constexpr int m4 = ML & 15;
  if constexpr (m4 == 1)       x = dpp_i<0xB1>(x);
  else if constexpr (m4 == 2)  x = dpp_i<0x4E>(x);
  else if constexpr (m4 == 3)  x = dpp_i<0x1B>(x);
  else if constexpr (m4 == 4)  { x = dpp_i<0x141>(x); x = dpp_i<0x1B>(x); }
  else if constexpr (m4 == 5)  { x = dpp_i<0x141>(x); x = dpp_i<0x4E>(x); }
  else if constexpr (m4 == 6)  { x = dpp_i<0x141>(x); x = dpp_i<0xB1>(x); }
  else if constexpr (m4 == 7)  x = dpp_i<0x141>(x);
  else if constexpr (m4 == 8)  x = dpp_i<0x128>(x);
  else if constexpr (m4 == 9)  { x = dpp_i<0x128>(x); x = dpp_i<0xB1>(x); }
  else if constexpr (m4 == 10) { x = dpp_i<0x128>(x); x = dpp_i<0x4E>(x); }
  else if constexpr (m4 == 11) { x = dpp_i<0x128>(x); x = dpp_i<0x1B>(x); }
  else if constexpr (m4 == 12) { x = dpp_i<0x140>(x); x = dpp_i<0x1B>(x); }
  else if constexpr (m4 == 13) { x = dpp_i<0x140>(x); x = dpp_i<0x4E>(x); }
  else if constexpr (m4 == 14) { x = dpp_i<0x140>(x); x = dpp_i<0xB1>(x); }
  else if constexpr (m4 == 15) x = dpp_i<0x140>(x);
  if constexpr (ML & 16) {
    v2i r = __builtin_amdgcn_permlane16_swap(x, x, false, false);
    x = (threadIdx.x & 16) ? r.x : r.y;
  }
  if constexpr (ML & 32) {
    v2i r = __builtin_amdgcn_permlane32_swap(x, x, false, false);
    x = (threadIdx.x & 32) ? r.x : r.y;
  }
  return __int_as_float(x);
}

// 64-lane sum of acc.x + acc.y.
__device__ __forceinline__ float redl(v2f acc) {
  float s = acc.x + acc.y;
  {
    v2i r = __builtin_amdgcn_permlane32_swap(__float_as_int(s),
                                             __float_as_int(s), false, false);
    s = __int_as_float(r.x) + __int_as_float(r.y);
  }
  {
    v2i r = __builtin_amdgcn_permlane16_swap(__float_as_int(s),
                                             __float_as_int(s), false, false);
    s = __int_as_float(r.x) + __int_as_float(r.y);
  }
  s += fetchx<8>(s);
  s += fetchx<4>(s);
  s += fetchx<2>(s);
  s += fetchx<1>(s);
  return s;
}

// Accumulate +-wts[g] (RAW angle; scale applied once after) into W[m & 7];
// sign = parity(tid & ((m>>3) & 0x1FF)).
template <int G>
__device__ __forceinline__ void accum_signs(float (&W)[8],
                                            const float* __restrict__ wts,
                                            int tid) {
  if constexpr (G < NGATES) {
    constexpr unsigned m = MK.rx[G];
    constexpr int mlo = (int)(m & 7u);
    constexpr int tmask = (int)((m >> 3) & 0x1FFu);
    const float th = wts[G];                 // uniform -> s_load, SGPR
    if constexpr (tmask == 0) {
      W[mlo] += th;
    } else {
      const int sgn = (__popc(tid & tmask) & 1) << 31;
      W[mlo] += __int_as_float(__float_as_int(th) ^ sgn);
    }
    accum_signs<G + 1>(W, wts, tid);
  }
}

// Is correlation lag w handled via the LDS stash?
constexpr bool is_lds(int w) {
  unsigned zm = MK.z[w];
  int tz = (int)((zm >> 3) & 0x1FFu);
  return (tz >> 6) != 0 || dppcost(tz & 63) > 2;
}

// Cheap lags: partner via DPP/permlane (lane bits only), 8-amp dot, reduce.
template <int W_>
__device__ __forceinline__ void corr_dpp(const v2f (&st)[8], float* zb,
                                         int lane, int wv) {
  if constexpr (W_ < NQ) {
    if constexpr (!is_lds(W_)) {
      constexpr unsigned zm = MK.z[W_];
      constexpr int mr = (int)(zm & 7u);
      constexpr int ml = (int)((zm >> 3) & 63u);
      v2f acc; acc.x = 0.f; acc.y = 0.f;
#pragma unroll
      for (int r = 0; r < 8; ++r) {
        v2f t;
        if constexpr (ml == 0) t = st[r ^ mr];
        else { t.x = fetchx<ml>(st[r ^ mr].x); t.y = fetchx<ml>(st[r ^ mr].y); }
        acc += st[r] * t;                    // v_pk_fma_f32
      }
      float s = redl(acc);
      if (lane == 0) zb[wv * NQ + W_] = s;
    }
    corr_dpp<W_ + 1>(st, zb, lane, wv);
  }
}

// LDS-stash lags: full st stashed once (slot k, thread t at xbuf[k*512+t]).
// Partner thread = tid ^ ((zm>>3) & 0x1FF); slot k serves local reg k^mr.
template <int W_>
__device__ __forceinline__ void corr_lds(const v2f (&st)[8],
                                         const v2f* xbuf, float* zb,
                                         int tid, int lane, int wv) {
  if constexpr (W_ < NQ) {
    if constexpr (is_lds(W_)) {
      constexpr unsigned zm = MK.z[W_];
      constexpr int mr = (int)(zm & 7u);
      constexpr int tz = (int)((zm >> 3) & 0x1FFu);
      const int ptid = tid ^ tz;
      v2f acc; acc.x = 0.f; acc.y = 0.f;
#pragma unroll
      for (int k = 0; k < 8; ++k)
        acc += st[k] * xbuf[(k ^ mr) * 512 + ptid];
      float s = redl(acc);
      if (lane == 0) zb[wv * NQ + W_] = s;
    }
    corr_lds<W_ + 1>(st, xbuf, zb, tid, lane, wv);
  }
}

__global__ __attribute__((amdgpu_flat_work_group_size(512, 512),
                          amdgpu_waves_per_eu(4)))
void qsim_kernel(const float* __restrict__ x,
                 const float* __restrict__ wts,
                 float* __restrict__ out) {
  __shared__ v2f xbuf[8 * 512];        // 32 KiB full-state stash
  __shared__ float zb[8 * NQ];
  __shared__ float a0s[NQ], a1s[NQ];   // per-element trig table

  const int bidx = blockIdx.x;         // one batch element per 512-thr block
  const int tid  = threadIdx.x;
  const int lane = tid & 63;
  const int wv   = tid >> 6;           // 0..7

  // ---- Phase 0: per-ELEMENT factors computed once (threads 0..11).
  // a0 = cy+sy (bit 0), a1 = cy-sy (bit 1); hw trig in revolutions.
  if (tid < NQ) {
    float rv = x[bidx * NQ + tid] * (0.5f * INV_2PI);
    float sy = __builtin_amdgcn_sinf(rv), cy = __builtin_amdgcn_cosf(rv);
    a0s[tid] = cy + sy;
    a1s[tid] = cy - sy;
  }
  __syncthreads();

  // ---- Phase 1: real product amplitude A from the LDS table.
  // tid bit i = p[3+i] = qubit (8-i), i=0..8; reg bit j = p[j] = qubit 11-j.
  float A[8];
  {
    float F = 0.015625f;                         // 2^-6 norm
#pragma unroll
    for (int i = 0; i <= 8; ++i)
      F *= ((tid >> i) & 1) ? a1s[8 - i] : a0s[8 - i];
    A[0] = F;
#pragma unroll
    for (int j = 0; j < 3; ++j) {                // reg bit j = qubit 11-j
      const float g0 = a0s[11 - j], g1 = a1s[11 - j];
#pragma unroll
      for (int k = 0; k < 4; ++k) {
        if (k < (1 << j)) {
          float base = A[k];
          A[k | (1 << j)] = base * g1;
          A[k]            = base * g0;
        }
      }
    }
  }

  // ---- Phase 2: Phi = signed accumulation of raw wts, scale once, 3-bit WHT.
  float W[8];
#pragma unroll
  for (int k = 0; k < 8; ++k) W[k] = 0.f;
  accum_signs<0>(W, wts, tid);
#pragma unroll
  for (int k = 0; k < 8; ++k) W[k] *= (0.5f * INV_2PI);   // th/2 -> revolutions
#pragma unroll
  for (int j = 0; j < 3; ++j) {
#pragma unroll
    for (int k = 0; k < 8; ++k) {
      if (!(k & (1 << j))) {
        float a = W[k], b = W[k | (1 << j)];
        W[k]            = a + b;
        W[k | (1 << j)] = a - b;
      }
    }
  }

  // ---- Phase 3: psi = A e^{-i Phi}; A and W die into st (16 VGPRs).
  v2f st[8];
#pragma unroll
  for (int r = 0; r < 8; ++r) {
    float s = __builtin_amdgcn_sinf(W[r]);
    float c = __builtin_amdgcn_cosf(W[r]);
    st[r].x = A[r] * c;
    st[r].y = -A[r] * s;
  }

  // ---- Phase 4: <Z_w> = sum_q Re[psi*(q^rho_w) psi(q)].
  // Stash write FIRST so DS-write latency hides under the DPP-lag VALU work.
#pragma unroll
  for (int k = 0; k < 8; ++k) xbuf[k * 512 + tid] = st[k];

  corr_dpp<0>(st, zb, lane, wv);

  __syncthreads();
  corr_lds<0>(st, xbuf, zb, tid, lane, wv);

  __syncthreads();
  if (tid < NQ) {
    float s = 0.f;
#pragma unroll
    for (int k = 0; k < 8; ++k) s += zb[k * NQ + tid];
    out[bidx * NQ + tid] = s;
  }
}

extern "C" void kernel_launch(void* const* d_in, const int* in_sizes, int n_in,
                              void* d_out, int out_size, void* d_ws, size_t ws_size,
                              hipStream_t stream) {
  const float* x   = (const float*)d_in[0];   // (4096, 12) f32
  const float* wts = (const float*)d_in[1];   // (4, 12) f32
  float* out = (float*)d_out;                 // (4096, 12) f32

  const int batch = in_sizes[0] / NQ;         // 4096
  dim3 grid(batch);
  dim3 block(512);
  qsim_kernel<<<grid, block, 0, stream>>>(x, wts, out);
}

// Round 21
// 33.216 us; speedup vs baseline: 1.2133x; 1.2133x over previous
//
#include <hip/hip_runtime.h>

#define NQ 12
#define NL 4
#define NGATES (NQ * NL)
#define INV_2PI 0.15915494309189535f

// ---------------------------------------------------------------------------
// Diagonalized formulation (r19 base: 256 thr/elem, 16 amps, wpe(3)).
// Every compiled gate is exp(-i th/2 X_m) -> all 48 commute; conjugating by
// H^x12 diagonalizes the circuit: U = H D H, D|q> = e^{-iPhi(q)}|q>,
//   Phi(q) = sum_g (th_g/2)(-1)^{parity(q & m_g)}  (layer-1 included).
// <Z_w> = sum_q conj(psi(q^rho_w)) psi(q), rho_w = row of L^-1 (HZH = X);
// psi = A e^{-iPhi}, A real product state (a0 = cy+sy, a1 = cy-sy, scale 2^-6).
// Layout (A = I): p[3:0] = reg (qubits 11..8), p[9:4] = lane bits 0..5
// (qubits 7..2), p[10] = tid6 (qubit 1), p[11] = tid7 (qubit 0).
// waves_per_eu(3) FINAL (wpe(4) spilled at this working set in r14/16/18;
// r20's 8-amp shape fit wpe(4) but doubled fixed per-thread work: 40 us).
// R21 CHANGE: phase 4 fetch work moved from VALU to the DS pipe. Old rule
// kept lags with dppcost<=2 on DPP (4 VALU/amp just for fetches); new rule
// keeps only dppcost<=1 lags on DPP - all others read partners from the
// ALREADY-STASHED state via ds_read_b64 (1 DS op + 1 pk_fma per amp; DS
// issues in parallel with other waves' VALU). Est. VALU/thread 950 -> ~750.
// xor-by-constant LDS addressing is a bijection on the low 5 addr bits ->
// bank-conflict-free.
// Per-element trig table in LDS (r18); raw-angle accumulation, scale once
// (r17); stash written before DPP lags so DS writes hide under VALU.
// ---------------------------------------------------------------------------
struct Masks { unsigned rx[NGATES]; unsigned z[NQ]; };

constexpr Masks compute_masks() {
  Masks mk{};
  unsigned col[NQ] = {};
  for (int b = 0; b < NQ; ++b) col[b] = 1u << b;
  int g = 0;
  for (int l = 0; l < NL; ++l) {
    for (int w = 0; w < NQ; ++w) mk.rx[g++] = col[NQ - 1 - w];
    for (int i = 0; i < NQ; ++i) {           // ring CNOT(i, (i+1)%12)
      int cb = NQ - 1 - i;
      int tb = NQ - 1 - ((i + 1) % NQ);
      col[cb] ^= col[tb];
    }
  }
  unsigned A[NQ] = {}, Inv[NQ] = {};
  for (int i = 0; i < NQ; ++i) {
    unsigned rowv = 0;
    for (int j = 0; j < NQ; ++j) rowv |= ((col[j] >> i) & 1u) << j;
    A[i] = rowv;
    Inv[i] = 1u << i;
  }
  for (int c = 0; c < NQ; ++c) {
    int piv = c;
    while (((A[piv] >> c) & 1u) == 0u) ++piv;
    unsigned ta = A[piv]; A[piv] = A[c]; A[c] = ta;
    unsigned ti = Inv[piv]; Inv[piv] = Inv[c]; Inv[c] = ti;
    for (int r = 0; r < NQ; ++r)
      if (r != c && ((A[r] >> c) & 1u)) { A[r] ^= A[c]; Inv[r] ^= Inv[c]; }
  }
  for (int w = 0; w < NQ; ++w) mk.z[w] = Inv[NQ - 1 - w];
  return mk;
}

constexpr Masks MK = compute_masks();

typedef float v2f __attribute__((ext_vector_type(2)));
typedef int   v2i __attribute__((ext_vector_type(2)));

template <int CTRL>
__device__ __forceinline__ int dpp_i(int x) {
  return __builtin_amdgcn_update_dpp(x, x, CTRL, 0xf, 0xf, false);
}

// VALU cost of a cross-lane xor-mask fetch (DPP/permlane path).
constexpr int dppcost(int ml) {
  int m4 = ml & 15;
  int c = (m4 == 0) ? 0
        : ((m4 == 1 || m4 == 2 || m4 == 3 || m4 == 7 || m4 == 8 || m4 == 15) ? 1 : 2);
  if (ml & 16) c += 2;
  if (ml & 32) c += 2;
  return c;
}

// v[lane ^ ML] on the VALU pipe. quad_perm xor1=0xB1 xor2=0x4E xor3=0x1B;
// row_half_mirror(xor7)=0x141; row_ror:8(xor8)=0x128; row_mirror(xor15)=0x140.
template <int ML>
__device__ __forceinline__ float fetchx(float v) {
  static_assert(ML >= 1 && ML < 64, "lane mask");
  int x = __float_as_int(v);
  constexpr int m4 = ML & 15;
  if constexpr (m4 == 1)       x = dpp_i<0xB1>(x);
  else if constexpr (m4 == 2)  x = dpp_i<0x4E>(x);
  else if constexpr (m4 == 3)  x = dpp_i<0x1B>(x);
  else if constexpr (m4 == 4)  { x = dpp_i<0x141>(x); x = dpp_i<0x1B>(x); }
  else if constexpr (m4 == 5)  { x = dpp_i<0x141>(x); x = dpp_i<0x4E>(x); }
  else if constexpr (m4 == 6)  { x = dpp_i<0x141>(x); x = dpp_i<0xB1>(x); }
  else if constexpr (m4 == 7)  x = dpp_i<0x141>(x);
  else if constexpr (m4 == 8)  x = dpp_i<0x128>(x);
  else if constexpr (m4 == 9)  { x = dpp_i<0x128>(x); x = dpp_i<0xB1>(x); }
  else if constexpr (m4 == 10) { x = dpp_i<0x128>(x); x = dpp_i<0x4E>(x); }
  else if constexpr (m4 == 11) { x = dpp_i<0x128>(x); x = dpp_i<0x1B>(x); }
  else if constexpr (m4 == 12) { x = dpp_i<0x140>(x); x = dpp_i<0x1B>(x); }
  else if constexpr (m4 == 13) { x = dpp_i<0x140>(x); x = dpp_i<0x4E>(x); }
  else if constexpr (m4 == 14) { x = dpp_i<0x140>(x); x = dpp_i<0xB1>(x); }
  else if constexpr (m4 == 15) x = dpp_i<0x140>(x);
  if constexpr (ML & 16) {
    v2i r = __builtin_amdgcn_permlane16_swap(x, x, false, false);
    x = (threadIdx.x & 16) ? r.x : r.y;
  }
  if constexpr (ML & 32) {
    v2i r = __builtin_amdgcn_permlane32_swap(x, x, false, false);
    x = (threadIdx.x & 32) ? r.x : r.y;
  }
  return __int_as_float(x);
}

// 64-lane sum of acc.x + acc.y.
__device__ __forceinline__ float redl(v2f acc) {
  float s = acc.x + acc.y;
  {
    v2i r = __builtin_amdgcn_permlane32_swap(__float_as_int(s),
                                             __float_as_int(s), false, false);
    s = __int_as_float(r.x) + __int_as_float(r.y);
  }
  {
    v2i r = __builtin_amdgcn_permlane16_swap(__float_as_int(s),
                                             __float_as_int(s), false, false);
    s = __int_as_float(r.x) + __int_as_float(r.y);
  }
  s += fetchx<8>(s);
  s += fetchx<4>(s);
  s += fetchx<2>(s);
  s += fetchx<1>(s);
  return s;
}

// Accumulate +-wts[g] (RAW angle; scale applied once after) into W[m & 15];
// sign = parity(tid & ((m>>4) & 0xFF)).
template <int G>
__device__ __forceinline__ void accum_signs(float (&W)[16],
                                            const float* __restrict__ wts,
                                            int tid) {
  if constexpr (G < NGATES) {
    constexpr unsigned m = MK.rx[G];
    constexpr int mlo = (int)(m & 15u);
    constexpr int tmask = (int)((m >> 4) & 0xFFu);
    const float th = wts[G];                 // uniform -> s_load, SGPR
    if constexpr (tmask == 0) {
      W[mlo] += th;
    } else {
      const int sgn = (__popc(tid & tmask) & 1) << 31;
      W[mlo] += __int_as_float(__float_as_int(th) ^ sgn);
    }
    accum_signs<G + 1>(W, wts, tid);
  }
}

// Is correlation lag w handled via the LDS stash?  (r21: threshold 2 -> 1;
// only single-DPP-fetch lags stay on the VALU path.)
constexpr bool is_lds(int w) {
  unsigned zm = MK.z[w];
  int tz = (int)((zm >> 4) & 0xFFu);
  return (tz >> 6) != 0 || dppcost(tz & 63) > 1;
}

// Cheap lags: partner via a single DPP/permlane op per fetch, 16-amp dot.
template <int W_>
__device__ __forceinline__ void corr_dpp(const v2f (&st)[16], float* zb,
                                         int lane, int wv) {
  if constexpr (W_ < NQ) {
    if constexpr (!is_lds(W_)) {
      constexpr unsigned zm = MK.z[W_];
      constexpr int mr = (int)(zm & 15u);
      constexpr int ml = (int)((zm >> 4) & 63u);
      v2f acc; acc.x = 0.f; acc.y = 0.f;
#pragma unroll
      for (int r = 0; r < 16; ++r) {
        v2f t;
        if constexpr (ml == 0) t = st[r ^ mr];
        else { t.x = fetchx<ml>(st[r ^ mr].x); t.y = fetchx<ml>(st[r ^ mr].y); }
        acc += st[r] * t;                    // v_pk_fma_f32
      }
      float s = redl(acc);
      if (lane == 0) zb[wv * NQ + W_] = s;
    }
    corr_dpp<W_ + 1>(st, zb, lane, wv);
  }
}

// LDS-stash lags: full st stashed once (slot k, thread t at xbuf[k*256+t]).
// Partner thread = tid ^ ((zm>>4) & 0xFF); slot k serves local reg k^mr.
template <int W_>
__device__ __forceinline__ void corr_lds(const v2f (&st)[16],
                                         const v2f* xbuf, float* zb,
                                         int tid, int lane, int wv) {
  if constexpr (W_ < NQ) {
    if constexpr (is_lds(W_)) {
      constexpr unsigned zm = MK.z[W_];
      constexpr int mr = (int)(zm & 15u);
      constexpr int tz = (int)((zm >> 4) & 0xFFu);
      const int ptid = tid ^ tz;
      v2f acc; acc.x = 0.f; acc.y = 0.f;
#pragma unroll
      for (int k = 0; k < 16; ++k)
        acc += st[k] * xbuf[(k ^ mr) * 256 + ptid];
      float s = redl(acc);
      if (lane == 0) zb[wv * NQ + W_] = s;
    }
    corr_lds<W_ + 1>(st, xbuf, zb, tid, lane, wv);
  }
}

__global__ __attribute__((amdgpu_flat_work_group_size(256, 256),
                          amdgpu_waves_per_eu(3)))
void qsim_kernel(const float* __restrict__ x,
                 const float* __restrict__ wts,
                 float* __restrict__ out) {
  __shared__ v2f xbuf[16 * 256];       // 32 KiB full-state stash
  __shared__ float zb[4 * NQ];
  __shared__ float a0s[NQ], a1s[NQ];   // per-element trig table

  const int bidx = blockIdx.x;         // one batch element per 256-thr block
  const int tid  = threadIdx.x;
  const int lane = tid & 63;
  const int wv   = tid >> 6;

  // ---- Phase 0: per-ELEMENT factors computed once (threads 0..11).
  // a0 = cy+sy (bit 0), a1 = cy-sy (bit 1); hw trig in revolutions.
  if (tid < NQ) {
    float rv = x[bidx * NQ + tid] * (0.5f * INV_2PI);
    float sy = __builtin_amdgcn_sinf(rv), cy = __builtin_amdgcn_cosf(rv);
    a0s[tid] = cy + sy;
    a1s[tid] = cy - sy;
  }
  __syncthreads();

  // ---- Phase 1: real product amplitude A from the LDS table.
  // Scalar: qubit 0 = tid7, qubit 1 = tid6, qubits 2..7 = tid bits 5..0.
  float A[16];
  {
    float F = 0.015625f * (((tid >> 7) & 1) ? a1s[0] : a0s[0]);   // 2^-6 norm
    F *= ((tid >> 6) & 1) ? a1s[1] : a0s[1];
#pragma unroll
    for (int w = 2; w <= 7; ++w)
      F *= ((tid >> (7 - w)) & 1) ? a1s[w] : a0s[w];
    A[0] = F;
#pragma unroll
    for (int j = 0; j < 4; ++j) {                // reg bit j = qubit 11-j
      const float g0 = a0s[11 - j], g1 = a1s[11 - j];
#pragma unroll
      for (int k = 0; k < 8; ++k) {
        if (k < (1 << j)) {
          float base = A[k];
          A[k | (1 << j)] = base * g1;
          A[k]            = base * g0;
        }
      }
    }
  }

  // ---- Phase 2: Phi = signed accumulation of raw wts, scale once, 4-bit WHT.
  float W[16];
#pragma unroll
  for (int k = 0; k < 16; ++k) W[k] = 0.f;
  accum_signs<0>(W, wts, tid);
#pragma unroll
  for (int k = 0; k < 16; ++k) W[k] *= (0.5f * INV_2PI);   // th/2 -> revolutions
#pragma unroll
  for (int j = 0; j < 4; ++j) {
#pragma unroll
    for (int k = 0; k < 16; ++k) {
      if (!(k & (1 << j))) {
        float a = W[k], b = W[k | (1 << j)];
        W[k]            = a + b;
        W[k | (1 << j)] = a - b;
      }
    }
  }

  // ---- Phase 3: psi = A e^{-i Phi}; A and W die into st (32 VGPRs).
  v2f st[16];
#pragma unroll
  for (int r = 0; r < 16; ++r) {
    float s = __builtin_amdgcn_sinf(W[r]);
    float c = __builtin_amdgcn_cosf(W[r]);
    st[r].x = A[r] * c;
    st[r].y = -A[r] * s;
  }

  // ---- Phase 4: <Z_w> = sum_q Re[psi*(q^rho_w) psi(q)].
  // Stash write FIRST so DS-write latency hides under the DPP-lag VALU work.
#pragma unroll
  for (int k = 0; k < 16; ++k) xbuf[k * 256 + tid] = st[k];

  corr_dpp<0>(st, zb, lane, wv);

  __syncthreads();
  corr_lds<0>(st, xbuf, zb, tid, lane, wv);

  __syncthreads();
  if (tid < NQ)
    out[bidx * NQ + tid] =
        zb[tid] + zb[NQ + tid] + zb[2 * NQ + tid] + zb[3 * NQ + tid];
}

extern "C" void kernel_launch(void* const* d_in, const int* in_sizes, int n_in,
                              void* d_out, int out_size, void* d_ws, size_t ws_size,
                              hipStream_t stream) {
  const float* x   = (const float*)d_in[0];   // (4096, 12) f32
  const float* wts = (const float*)d_in[1];   // (4, 12) f32
  float* out = (float*)d_out;                 // (4096, 12) f32

  const int batch = in_sizes[0] / NQ;         // 4096
  dim3 grid(batch);
  dim3 block(256);
  qsim_kernel<<<grid, block, 0, stream>>>(x, wts, out);
}

// Round 22
// 30.346 us; speedup vs baseline: 1.3280x; 1.0946x over previous
//
#include <hip/hip_runtime.h>

#define NQ 12
#define NL 4
#define NGATES (NQ * NL)
#define INV_2PI 0.15915494309189535f

// ---------------------------------------------------------------------------
// Diagonalized formulation (r21 base: 256 thr/elem, 16 amps, wpe(3)).
// U = H D H diagonal; Phi(q) = sum_g (th_g/2)(-1)^{parity(q & m_g)};
// <Z_w> = sum_q conj(psi(q^rho_w)) psi(q); psi = A e^{-iPhi}, A real product
// state (a0 = cy+sy, a1 = cy-sy, scale 2^-6).
// Layout (A = I): p[3:0] = reg (qubits 11..8), p[9:4] = lane bits 0..5
// (qubits 7..2), p[10] = tid6 (qubit 1), p[11] = tid7 (qubit 0).
// waves_per_eu(3) FINAL (wpe(4) spills at this working set: r14/16/18).
// R22 CHANGE: reduction epilogue parallelized across waves. Old: 12 lags x
// (6-level cross-lane tree, serially dependent) per thread (~144 VALU +
// ~600 dependent cycles). New: each thread writes 12 per-lag partials to
// zacc[12][256] (LDS), barrier, wave w reduces outputs 3w..3w+2: 1
// ds_read_b128 (4 contiguous floats/lane) + 3 adds + ONE tree, lane 0
// stores directly to global. 12 serial trees -> 3, running in parallel on
// the 4 waves; zb staging + final sum block deleted.
// Per-element trig table in LDS (r18); raw-angle accumulation, scale once
// (r17); stash written before DPP lags (r17); DS-pipe lag fetches (r21).
// ---------------------------------------------------------------------------
struct Masks { unsigned rx[NGATES]; unsigned z[NQ]; };

constexpr Masks compute_masks() {
  Masks mk{};
  unsigned col[NQ] = {};
  for (int b = 0; b < NQ; ++b) col[b] = 1u << b;
  int g = 0;
  for (int l = 0; l < NL; ++l) {
    for (int w = 0; w < NQ; ++w) mk.rx[g++] = col[NQ - 1 - w];
    for (int i = 0; i < NQ; ++i) {           // ring CNOT(i, (i+1)%12)
      int cb = NQ - 1 - i;
      int tb = NQ - 1 - ((i + 1) % NQ);
      col[cb] ^= col[tb];
    }
  }
  unsigned A[NQ] = {}, Inv[NQ] = {};
  for (int i = 0; i < NQ; ++i) {
    unsigned rowv = 0;
    for (int j = 0; j < NQ; ++j) rowv |= ((col[j] >> i) & 1u) << j;
    A[i] = rowv;
    Inv[i] = 1u << i;
  }
  for (int c = 0; c < NQ; ++c) {
    int piv = c;
    while (((A[piv] >> c) & 1u) == 0u) ++piv;
    unsigned ta = A[piv]; A[piv] = A[c]; A[c] = ta;
    unsigned ti = Inv[piv]; Inv[piv] = Inv[c]; Inv[c] = ti;
    for (int r = 0; r < NQ; ++r)
      if (r != c && ((A[r] >> c) & 1u)) { A[r] ^= A[c]; Inv[r] ^= Inv[c]; }
  }
  for (int w = 0; w < NQ; ++w) mk.z[w] = Inv[NQ - 1 - w];
  return mk;
}

constexpr Masks MK = compute_masks();

typedef float v2f __attribute__((ext_vector_type(2)));
typedef int   v2i __attribute__((ext_vector_type(2)));

template <int CTRL>
__device__ __forceinline__ int dpp_i(int x) {
  return __builtin_amdgcn_update_dpp(x, x, CTRL, 0xf, 0xf, false);
}

// VALU cost of a cross-lane xor-mask fetch (DPP/permlane path).
constexpr int dppcost(int ml) {
  int m4 = ml & 15;
  int c = (m4 == 0) ? 0
        : ((m4 == 1 || m4 == 2 || m4 == 3 || m4 == 7 || m4 == 8 || m4 == 15) ? 1 : 2);
  if (ml & 16) c += 2;
  if (ml & 32) c += 2;
  return c;
}

// v[lane ^ ML] on the VALU pipe. quad_perm xor1=0xB1 xor2=0x4E xor3=0x1B;
// row_half_mirror(xor7)=0x141; row_ror:8(xor8)=0x128; row_mirror(xor15)=0x140.
template <int ML>
__device__ __forceinline__ float fetchx(float v) {
  static_assert(ML >= 1 && ML < 64, "lane mask");
  int x = __float_as_int(v);
  constexpr int m4 = ML & 15;
  if constexpr (m4 == 1)       x = dpp_i<0xB1>(x);
  else if constexpr (m4 == 2)  x = dpp_i<0x4E>(x);
  else if constexpr (m4 == 3)  x = dpp_i<0x1B>(x);
  else if constexpr (m4 == 4)  { x = dpp_i<0x141>(x); x = dpp_i<0x1B>(x); }
  else if constexpr (m4 == 5)  { x = dpp_i<0x141>(x); x = dpp_i<0x4E>(x); }
  else if constexpr (m4 == 6)  { x = dpp_i<0x141>(x); x = dpp_i<0xB1>(x); }
  else if constexpr (m4 == 7)  x = dpp_i<0x141>(x);
  else if constexpr (m4 == 8)  x = dpp_i<0x128>(x);
  else if constexpr (m4 == 9)  { x = dpp_i<0x128>(x); x = dpp_i<0xB1>(x); }
  else if constexpr (m4 == 10) { x = dpp_i<0x128>(x); x = dpp_i<0x4E>(x); }
  else if constexpr (m4 == 11) { x = dpp_i<0x128>(x); x = dpp_i<0x1B>(x); }
  else if constexpr (m4 == 12) { x = dpp_i<0x140>(x); x = dpp_i<0x1B>(x); }
  else if constexpr (m4 == 13) { x = dpp_i<0x140>(x); x = dpp_i<0x4E>(x); }
  else if constexpr (m4 == 14) { x = dpp_i<0x140>(x); x = dpp_i<0xB1>(x); }
  else if constexpr (m4 == 15) x = dpp_i<0x140>(x);
  if constexpr (ML & 16) {
    v2i r = __builtin_amdgcn_permlane16_swap(x, x, false, false);
    x = (threadIdx.x & 16) ? r.x : r.y;
  }
  if constexpr (ML & 32) {
    v2i r = __builtin_amdgcn_permlane32_swap(x, x, false, false);
    x = (threadIdx.x & 32) ? r.x : r.y;
  }
  return __int_as_float(x);
}

// 64-lane sum of scalar s.
__device__ __forceinline__ float redl_s(float s) {
  {
    v2i r = __builtin_amdgcn_permlane32_swap(__float_as_int(s),
                                             __float_as_int(s), false, false);
    s = __int_as_float(r.x) + __int_as_float(r.y);
  }
  {
    v2i r = __builtin_amdgcn_permlane16_swap(__float_as_int(s),
                                             __float_as_int(s), false, false);
    s = __int_as_float(r.x) + __int_as_float(r.y);
  }
  s += fetchx<8>(s);
  s += fetchx<4>(s);
  s += fetchx<2>(s);
  s += fetchx<1>(s);
  return s;
}

// Accumulate +-wts[g] (RAW angle; scale applied once after) into W[m & 15];
// sign = parity(tid & ((m>>4) & 0xFF)).
template <int G>
__device__ __forceinline__ void accum_signs(float (&W)[16],
                                            const float* __restrict__ wts,
                                            int tid) {
  if constexpr (G < NGATES) {
    constexpr unsigned m = MK.rx[G];
    constexpr int mlo = (int)(m & 15u);
    constexpr int tmask = (int)((m >> 4) & 0xFFu);
    const float th = wts[G];                 // uniform -> s_load, SGPR
    if constexpr (tmask == 0) {
      W[mlo] += th;
    } else {
      const int sgn = (__popc(tid & tmask) & 1) << 31;
      W[mlo] += __int_as_float(__float_as_int(th) ^ sgn);
    }
    accum_signs<G + 1>(W, wts, tid);
  }
}

// Is correlation lag w handled via the LDS stash?  (threshold: dppcost > 1.)
constexpr bool is_lds(int w) {
  unsigned zm = MK.z[w];
  int tz = (int)((zm >> 4) & 0xFFu);
  return (tz >> 6) != 0 || dppcost(tz & 63) > 1;
}

// Cheap lags: partner via a single DPP/permlane op per fetch, 16-amp dot;
// per-thread partial written to zacc (no tree here - r22).
template <int W_>
__device__ __forceinline__ void corr_dpp(const v2f (&st)[16], float* zacc,
                                         int tid) {
  if constexpr (W_ < NQ) {
    if constexpr (!is_lds(W_)) {
      constexpr unsigned zm = MK.z[W_];
      constexpr int mr = (int)(zm & 15u);
      constexpr int ml = (int)((zm >> 4) & 63u);
      v2f acc; acc.x = 0.f; acc.y = 0.f;
#pragma unroll
      for (int r = 0; r < 16; ++r) {
        v2f t;
        if constexpr (ml == 0) t = st[r ^ mr];
        else { t.x = fetchx<ml>(st[r ^ mr].x); t.y = fetchx<ml>(st[r ^ mr].y); }
        acc += st[r] * t;                    // v_pk_fma_f32
      }
      zacc[W_ * 256 + tid] = acc.x + acc.y;
    }
    corr_dpp<W_ + 1>(st, zacc, tid);
  }
}

// LDS-stash lags: full st stashed once (slot k, thread t at xbuf[k*256+t]).
// Partner thread = tid ^ ((zm>>4) & 0xFF); slot k serves local reg k^mr.
template <int W_>
__device__ __forceinline__ void corr_lds(const v2f (&st)[16],
                                         const v2f* xbuf, float* zacc,
                                         int tid) {
  if constexpr (W_ < NQ) {
    if constexpr (is_lds(W_)) {
      constexpr unsigned zm = MK.z[W_];
      constexpr int mr = (int)(zm & 15u);
      constexpr int tz = (int)((zm >> 4) & 0xFFu);
      const int ptid = tid ^ tz;
      v2f acc; acc.x = 0.f; acc.y = 0.f;
#pragma unroll
      for (int k = 0; k < 16; ++k)
        acc += st[k] * xbuf[(k ^ mr) * 256 + ptid];
      zacc[W_ * 256 + tid] = acc.x + acc.y;
    }
    corr_lds<W_ + 1>(st, xbuf, zacc, tid);
  }
}

__global__ __attribute__((amdgpu_flat_work_group_size(256, 256),
                          amdgpu_waves_per_eu(3)))
void qsim_kernel(const float* __restrict__ x,
                 const float* __restrict__ wts,
                 float* __restrict__ out) {
  __shared__ v2f xbuf[16 * 256];       // 32 KiB full-state stash
  __shared__ float zacc[NQ * 256];     // 12 KiB per-thread lag partials
  __shared__ float a0s[NQ], a1s[NQ];   // per-element trig table

  const int bidx = blockIdx.x;         // one batch element per 256-thr block
  const int tid  = threadIdx.x;
  const int lane = tid & 63;
  const int wv   = tid >> 6;

  // ---- Phase 0: per-ELEMENT factors computed once (threads 0..11).
  // a0 = cy+sy (bit 0), a1 = cy-sy (bit 1); hw trig in revolutions.
  if (tid < NQ) {
    float rv = x[bidx * NQ + tid] * (0.5f * INV_2PI);
    float sy = __builtin_amdgcn_sinf(rv), cy = __builtin_amdgcn_cosf(rv);
    a0s[tid] = cy + sy;
    a1s[tid] = cy - sy;
  }
  __syncthreads();

  // ---- Phase 1: real product amplitude A from the LDS table.
  // Scalar: qubit 0 = tid7, qubit 1 = tid6, qubits 2..7 = tid bits 5..0.
  float A[16];
  {
    float F = 0.015625f * (((tid >> 7) & 1) ? a1s[0] : a0s[0]);   // 2^-6 norm
    F *= ((tid >> 6) & 1) ? a1s[1] : a0s[1];
#pragma unroll
    for (int w = 2; w <= 7; ++w)
      F *= ((tid >> (7 - w)) & 1) ? a1s[w] : a0s[w];
    A[0] = F;
#pragma unroll
    for (int j = 0; j < 4; ++j) {                // reg bit j = qubit 11-j
      const float g0 = a0s[11 - j], g1 = a1s[11 - j];
#pragma unroll
      for (int k = 0; k < 8; ++k) {
        if (k < (1 << j)) {
          float base = A[k];
          A[k | (1 << j)] = base * g1;
          A[k]            = base * g0;
        }
      }
    }
  }

  // ---- Phase 2: Phi = signed accumulation of raw wts, scale once, 4-bit WHT.
  float W[16];
#pragma unroll
  for (int k = 0; k < 16; ++k) W[k] = 0.f;
  accum_signs<0>(W, wts, tid);
#pragma unroll
  for (int k = 0; k < 16; ++k) W[k] *= (0.5f * INV_2PI);   // th/2 -> revolutions
#pragma unroll
  for (int j = 0; j < 4; ++j) {
#pragma unroll
    for (int k = 0; k < 16; ++k) {
      if (!(k & (1 << j))) {
        float a = W[k], b = W[k | (1 << j)];
        W[k]            = a + b;
        W[k | (1 << j)] = a - b;
      }
    }
  }

  // ---- Phase 3: psi = A e^{-i Phi}; A and W die into st (32 VGPRs).
  v2f st[16];
#pragma unroll
  for (int r = 0; r < 16; ++r) {
    float s = __builtin_amdgcn_sinf(W[r]);
    float c = __builtin_amdgcn_cosf(W[r]);
    st[r].x = A[r] * c;
    st[r].y = -A[r] * s;
  }

  // ---- Phase 4: <Z_w> partials. Stash write FIRST (DS latency hides under
  // the DPP-lag VALU), then DPP lags, barrier, LDS lags. No trees here.
#pragma unroll
  for (int k = 0; k < 16; ++k) xbuf[k * 256 + tid] = st[k];

  corr_dpp<0>(st, zacc, tid);

  __syncthreads();
  corr_lds<0>(st, xbuf, zacc, tid);

  // ---- Phase 5: cross-wave reduction, 3 outputs per wave in parallel.
  __syncthreads();
#pragma unroll
  for (int j = 0; j < 3; ++j) {
    const int w = wv * 3 + j;
    const float4 v = *reinterpret_cast<const float4*>(&zacc[w * 256 + lane * 4]);
    float s = (v.x + v.y) + (v.z + v.w);
    s = redl_s(s);
    if (lane == 0) out[bidx * NQ + w] = s;
  }
}

extern "C" void kernel_launch(void* const* d_in, const int* in_sizes, int n_in,
                              void* d_out, int out_size, void* d_ws, size_t ws_size,
                              hipStream_t stream) {
  const float* x   = (const float*)d_in[0];   // (4096, 12) f32
  const float* wts = (const float*)d_in[1];   // (4, 12) f32
  float* out = (float*)d_out;                 // (4096, 12) f32

  const int batch = in_sizes[0] / NQ;         // 4096
  dim3 grid(batch);
  dim3 block(256);
  qsim_kernel<<<grid, block, 0, stream>>>(x, wts, out);
}